// Round 2
// baseline (7261.743 us; speedup 1.0000x reference)
//
#include <hip/hip_runtime.h>

#define HDIM 64
#define NSTEPS 4

typedef float v4f __attribute__((ext_vector_type(4)));

// Packed weight layout in d_ws (float offsets):
//   [0,    256): L1 pack: per k, float4 (W1[k][0], W1[k][1], W1[k][2], b1[k])
//   [256, 4352): W2T[k][j] = W2[j][k+1]                  (64x64)
//   [4352,8448): QT[k][j]  = P[k][j] * W2[j][k+1]        (64x64)
//                where P[k][j] = W1[k][1]*W3[0][j+1] + W1[k][2]*W3[1][j+1]
//   [8448,8576): C2 per j: float2 (W2[j][0], b2[j])
//   [8576,8704): L3 per j: float2 (W3[0][j+1], W3[1][j+1])
//   [8704,8708): C3: (W3[0][0], W3[1][0], b3[0], b3[1])

__global__ void ffjord_prep(const float* __restrict__ W1, const float* __restrict__ b1,
                            const float* __restrict__ W2, const float* __restrict__ b2,
                            const float* __restrict__ W3, const float* __restrict__ b3,
                            float* __restrict__ ws) {
  int tid = threadIdx.x;  // single block, 256 threads
  if (tid < HDIM) {
    ws[tid * 4 + 0] = W1[tid * 3 + 0];
    ws[tid * 4 + 1] = W1[tid * 3 + 1];
    ws[tid * 4 + 2] = W1[tid * 3 + 2];
    ws[tid * 4 + 3] = b1[tid];
    ws[8448 + tid * 2 + 0] = W2[tid * 65 + 0];
    ws[8448 + tid * 2 + 1] = b2[tid];
    ws[8576 + tid * 2 + 0] = W3[0 * 65 + tid + 1];
    ws[8576 + tid * 2 + 1] = W3[1 * 65 + tid + 1];
  }
  if (tid == 0) {
    ws[8704] = W3[0];
    ws[8705] = W3[65];
    ws[8706] = b3[0];
    ws[8707] = b3[1];
  }
  for (int e = tid; e < HDIM * HDIM; e += 256) {
    int k = e >> 6, j = e & 63;
    float w2 = W2[j * 65 + k + 1];
    float p = W1[k * 3 + 1] * W3[j + 1] + W1[k * 3 + 2] * W3[65 + j + 1];
    ws[256 + e] = w2;       // W2T[k][j]
    ws[4352 + e] = p * w2;  // QT[k][j]
  }
}

// Two lanes per point: lane pair (2p, 2p+1); half = t&1 owns j in [half*32, half*32+32).
// Live state per thread: h2[8] v4f (32 regs) + scalars -> fits well under the
// 128-reg cap of __launch_bounds__(256,2); (256,4) proved to cap at 64 and spill.
__global__ __launch_bounds__(256, 2) void ffjord_main(
    const float* __restrict__ z_in, const float* __restrict__ dlp_in,
    const float* __restrict__ ws, float* __restrict__ out, int B) {
  int t = blockIdx.x * 256 + threadIdx.x;
  int i = t >> 1;    // point index
  int half = t & 1;  // which 32-wide j-slice this lane owns
  if (i >= B) return;

  const float4* L1  = (const float4*)(ws);
  const float*  W2T = ws + 256  + half * 32;   // row base pre-offset by half
  const float*  QT  = ws + 4352 + half * 32;
  const float2* C2  = (const float2*)(ws + 8448) + half * 32;
  const float2* L3  = (const float2*)(ws + 8576) + half * 32;
  const float c30 = ws[8704], c31 = ws[8705], cb0 = ws[8706], cb1 = ws[8707];

  float z0 = z_in[2 * i], z1 = z_in[2 * i + 1];
  float l = dlp_in[i];
  const float dt = 1.0f / NSTEPS;

  #pragma unroll 1
  for (int step = 0; step < NSTEPS; ++step) {
    float t0 = step * dt;
    float az0 = 0.f, az1 = 0.f, al = 0.f;
    float zt0 = z0, zt1 = z1, ts = t0;

    #pragma unroll 1
    for (int s = 0; s < 4; ++s) {
      // ---- dynamics eval at (ts, zt) ----
      // Pass A: h2[j] = W2[:,0]*t + b2 + sum_k W2T[k][j] * softplus(a_k)   (my 32 j's)
      v4f h2[8];
      #pragma unroll
      for (int m = 0; m < 8; ++m) {
        float2 c0 = C2[4 * m + 0], c1 = C2[4 * m + 1];
        float2 c2 = C2[4 * m + 2], c3 = C2[4 * m + 3];
        v4f v;
        v.x = fmaf(c0.x, ts, c0.y);
        v.y = fmaf(c1.x, ts, c1.y);
        v.z = fmaf(c2.x, ts, c2.y);
        v.w = fmaf(c3.x, ts, c3.y);
        h2[m] = v;
      }

      #pragma unroll 1
      for (int k = 0; k < HDIM; ++k) {
        float4 w1 = L1[k];  // uniform address -> s_load
        float a = fmaf(w1.x, ts, fmaf(w1.y, zt0, fmaf(w1.z, zt1, w1.w)));
        float e = __expf(-fabsf(a));
        float sp = fmaxf(a, 0.f) + __logf(1.0f + e);   // softplus(a)
        const v4f* w2row = (const v4f*)(W2T + k * 64);
        v4f spv = {sp, sp, sp, sp};
        #pragma unroll
        for (int m = 0; m < 8; ++m)
          h2[m] = __builtin_elementwise_fma(w2row[m], spv, h2[m]);
      }

      // Mid: zd partials over my j's; overwrite h2 with g = sigmoid(h2)
      float zd0p = 0.f, zd1p = 0.f;
      #pragma unroll
      for (int m = 0; m < 8; ++m) {
        v4f hv = h2[m];
        v4f gv;
        #pragma unroll
        for (int c = 0; c < 4; ++c) {
          float a = hv[c];
          float e = __expf(-fabsf(a));
          float r = __builtin_amdgcn_rcpf(1.0f + e);
          float sg = (a >= 0.f ? 1.0f : e) * r;        // sigmoid
          float sp = fmaxf(a, 0.f) + __logf(1.0f + e); // softplus
          float2 l3 = L3[4 * m + c];
          zd0p = fmaf(l3.x, sp, zd0p);
          zd1p = fmaf(l3.y, sp, zd1p);
          gv[c] = sg;
        }
        h2[m] = gv;  // now holds g
      }

      // Pass B: dv partial = sum_k sigmoid(a_k) * (QT[k][my j's] . g)
      float dv = 0.f;
      #pragma unroll 1
      for (int k = 0; k < HDIM; ++k) {
        float4 w1 = L1[k];
        float a = fmaf(w1.x, ts, fmaf(w1.y, zt0, fmaf(w1.z, zt1, w1.w)));
        float e = __expf(-fabsf(a));
        float r = __builtin_amdgcn_rcpf(1.0f + e);
        float sg = (a >= 0.f ? 1.0f : e) * r;          // sigmoid(a_k)
        const v4f* qrow = (const v4f*)(QT + k * 64);
        v4f d0 = {0.f, 0.f, 0.f, 0.f}, d1 = {0.f, 0.f, 0.f, 0.f};
        #pragma unroll
        for (int m = 0; m < 8; m += 2) {
          d0 = __builtin_elementwise_fma(qrow[m], h2[m], d0);
          d1 = __builtin_elementwise_fma(qrow[m + 1], h2[m + 1], d1);
        }
        v4f ds = d0 + d1;
        float dot = (ds.x + ds.y) + (ds.z + ds.w);
        dv = fmaf(sg, dot, dv);
      }

      // ---- combine partials across the lane pair (same wave, adjacent lanes) ----
      zd0p += __shfl_xor(zd0p, 1);
      zd1p += __shfl_xor(zd1p, 1);
      dv   += __shfl_xor(dv, 1);
      float zd0 = zd0p + fmaf(c30, ts, cb0);  // base term added once, after reduce
      float zd1 = zd1p + fmaf(c31, ts, cb1);

      // ---- RK4 combine (both lanes hold identical zd/dv -> stay in lockstep) ----
      float w = (s == 1 || s == 2) ? 2.0f : 1.0f;
      az0 = fmaf(w, zd0, az0);
      az1 = fmaf(w, zd1, az1);
      al = fmaf(w, dv, al);
      if (s < 3) {
        float c = (s == 2) ? dt : 0.5f * dt;
        zt0 = fmaf(c, zd0, z0);
        zt1 = fmaf(c, zd1, z1);
        ts = t0 + c;
      }
    }
    z0 = fmaf(dt / 6.0f, az0, z0);
    z1 = fmaf(dt / 6.0f, az1, z1);
    l = fmaf(-dt / 6.0f, al, l);  // k_l = -div
  }

  if (half == 0) {
    out[2 * i] = z0;
    out[2 * i + 1] = z1;
  } else {
    out[2 * B + i] = l;
  }
}

extern "C" void kernel_launch(void* const* d_in, const int* in_sizes, int n_in,
                              void* d_out, int out_size, void* d_ws, size_t ws_size,
                              hipStream_t stream) {
  const float* z   = (const float*)d_in[0];
  const float* dlp = (const float*)d_in[1];
  const float* W1  = (const float*)d_in[2];
  const float* b1  = (const float*)d_in[3];
  const float* W2  = (const float*)d_in[4];
  const float* b2  = (const float*)d_in[5];
  const float* W3  = (const float*)d_in[6];
  const float* b3  = (const float*)d_in[7];
  float* out = (float*)d_out;
  float* ws = (float*)d_ws;

  int B = in_sizes[0] / 2;

  ffjord_prep<<<1, 256, 0, stream>>>(W1, b1, W2, b2, W3, b3, ws);
  int blocks = (2 * B + 255) / 256;  // two lanes per point
  ffjord_main<<<blocks, 256, 0, stream>>>(z, dlp, ws, out, B);
}

// Round 3
// 2146.171 us; speedup vs baseline: 3.3836x; 3.3836x over previous
//
#include <hip/hip_runtime.h>

#define HDIM 64
#define NSTEPS 4

typedef float v2f __attribute__((ext_vector_type(2)));

// Packed weight layout in d_ws (float offsets):
//   [0,    256): L1 pack: per k, float4 (W1[k][0], W1[k][1], W1[k][2], b1[k])
//   [256, 4352): W2T[k][j] = W2[j][k+1]                  (64x64)
//   [4352,8448): QT[k][j]  = P[k][j] * W2[j][k+1]        (64x64)
//                where P[k][j] = W1[k][1]*W3[0][j+1] + W1[k][2]*W3[1][j+1]
//   [8448,8576): C2 per j: float2 (W2[j][0], b2[j])
//   [8576,8704): L3 per j: float2 (W3[0][j+1], W3[1][j+1])
//   [8704,8708): C3: (W3[0][0], W3[1][0], b3[0], b3[1])

__global__ void ffjord_prep(const float* __restrict__ W1, const float* __restrict__ b1,
                            const float* __restrict__ W2, const float* __restrict__ b2,
                            const float* __restrict__ W3, const float* __restrict__ b3,
                            float* __restrict__ ws) {
  int tid = threadIdx.x;  // single block, 256 threads
  if (tid < HDIM) {
    ws[tid * 4 + 0] = W1[tid * 3 + 0];
    ws[tid * 4 + 1] = W1[tid * 3 + 1];
    ws[tid * 4 + 2] = W1[tid * 3 + 2];
    ws[tid * 4 + 3] = b1[tid];
    ws[8448 + tid * 2 + 0] = W2[tid * 65 + 0];
    ws[8448 + tid * 2 + 1] = b2[tid];
    ws[8576 + tid * 2 + 0] = W3[0 * 65 + tid + 1];
    ws[8576 + tid * 2 + 1] = W3[1 * 65 + tid + 1];
  }
  if (tid == 0) {
    ws[8704] = W3[0];
    ws[8705] = W3[65];
    ws[8706] = b3[0];
    ws[8707] = b3[1];
  }
  for (int e = tid; e < HDIM * HDIM; e += 256) {
    int k = e >> 6, j = e & 63;
    float w2 = W2[j * 65 + k + 1];
    float p = W1[k * 3 + 1] * W3[j + 1] + W1[k * 3 + 2] * W3[65 + j + 1];
    ws[256 + e] = w2;       // W2T[k][j]
    ws[4352 + e] = p * w2;  // QT[k][j]
  }
}

// One point per thread (all weight-row addresses wave-uniform -> s_load path).
// Two-pass divergence: pass B recomputes layer-1 activations, so q[64] is never
// materialized; peak live state is h2/g (32 v2f = 64 regs) + temps.
// __launch_bounds__(256,2): reg cap 256 -> no spill possible (the (256,4) 64-reg
// cap was round 1's failure; lane-divergent rows were round 2's).
__global__ __launch_bounds__(256, 2) void ffjord_main(
    const float* __restrict__ z_in, const float* __restrict__ dlp_in,
    const float* __restrict__ ws, float* __restrict__ out, int B) {
  int i = blockIdx.x * 256 + threadIdx.x;
  if (i >= B) return;

  const float4* L1  = (const float4*)(ws);
  const float*  W2T = ws + 256;
  const float*  QT  = ws + 4352;
  const float2* C2  = (const float2*)(ws + 8448);
  const float2* L3  = (const float2*)(ws + 8576);
  const float c30 = ws[8704], c31 = ws[8705], cb0 = ws[8706], cb1 = ws[8707];

  float z0 = z_in[2 * i], z1 = z_in[2 * i + 1];
  float l = dlp_in[i];
  const float dt = 1.0f / NSTEPS;

  #pragma unroll 1
  for (int step = 0; step < NSTEPS; ++step) {
    float t0 = step * dt;
    float az0 = 0.f, az1 = 0.f, al = 0.f;
    float zt0 = z0, zt1 = z1, ts = t0;

    #pragma unroll 1
    for (int s = 0; s < 4; ++s) {
      // ---- dynamics eval at (ts, zt) ----
      // Pass A: h2[j] = W2[:,0]*t + b2 + sum_k W2T[k][j] * softplus(a_k)
      v2f h2[HDIM / 2];
      #pragma unroll
      for (int jj = 0; jj < HDIM / 2; ++jj) {
        float2 ca = C2[2 * jj], cb2 = C2[2 * jj + 1];
        v2f v;
        v.x = fmaf(ca.x, ts, ca.y);
        v.y = fmaf(cb2.x, ts, cb2.y);
        h2[jj] = v;
      }

      #pragma unroll 1
      for (int k = 0; k < HDIM; ++k) {
        float4 w1 = L1[k];  // wave-uniform -> scalar load
        float a = fmaf(w1.x, ts, fmaf(w1.y, zt0, fmaf(w1.z, zt1, w1.w)));
        float e = __expf(-fabsf(a));
        float sp = fmaxf(a, 0.f) + __logf(1.0f + e);   // softplus(a)
        const v2f* w2row = (const v2f*)(W2T + k * 64); // wave-uniform row
        v2f spv = {sp, sp};
        #pragma unroll
        for (int jj = 0; jj < HDIM / 2; ++jj)
          h2[jj] = __builtin_elementwise_fma(w2row[jj], spv, h2[jj]);
      }

      // Mid: zd += L3 * softplus(h2); overwrite h2 with g = sigmoid(h2)
      float zd0 = fmaf(c30, ts, cb0);
      float zd1 = fmaf(c31, ts, cb1);
      #pragma unroll
      for (int jj = 0; jj < HDIM / 2; ++jj) {
        v2f hv = h2[jj];
        v2f gv;
        #pragma unroll
        for (int c = 0; c < 2; ++c) {
          float a = hv[c];
          float e = __expf(-fabsf(a));
          float r = __builtin_amdgcn_rcpf(1.0f + e);
          float sg = (a >= 0.f ? 1.0f : e) * r;        // sigmoid
          float sp = fmaxf(a, 0.f) + __logf(1.0f + e); // softplus
          float2 l3 = L3[2 * jj + c];
          zd0 = fmaf(l3.x, sp, zd0);
          zd1 = fmaf(l3.y, sp, zd1);
          gv[c] = sg;
        }
        h2[jj] = gv;  // now holds g
      }

      // Pass B: dv = sum_k sigmoid(a_k) * (QT[k] . g)   (a_k recomputed, cheap)
      float dv = 0.f;
      #pragma unroll 1
      for (int k = 0; k < HDIM; ++k) {
        float4 w1 = L1[k];
        float a = fmaf(w1.x, ts, fmaf(w1.y, zt0, fmaf(w1.z, zt1, w1.w)));
        float e = __expf(-fabsf(a));
        float r = __builtin_amdgcn_rcpf(1.0f + e);
        float sg = (a >= 0.f ? 1.0f : e) * r;          // sigmoid(a_k)
        const v2f* qrow = (const v2f*)(QT + k * 64);   // wave-uniform row
        v2f a0 = {0.f, 0.f}, a1 = {0.f, 0.f}, a2 = {0.f, 0.f}, a3 = {0.f, 0.f};
        #pragma unroll
        for (int jj = 0; jj < 8; ++jj) {
          a0 = __builtin_elementwise_fma(qrow[4 * jj + 0], h2[4 * jj + 0], a0);
          a1 = __builtin_elementwise_fma(qrow[4 * jj + 1], h2[4 * jj + 1], a1);
          a2 = __builtin_elementwise_fma(qrow[4 * jj + 2], h2[4 * jj + 2], a2);
          a3 = __builtin_elementwise_fma(qrow[4 * jj + 3], h2[4 * jj + 3], a3);
        }
        v2f sab = (a0 + a1) + (a2 + a3);
        dv = fmaf(sg, sab.x + sab.y, dv);
      }

      // ---- RK4 combine ----
      float w = (s == 1 || s == 2) ? 2.0f : 1.0f;
      az0 = fmaf(w, zd0, az0);
      az1 = fmaf(w, zd1, az1);
      al = fmaf(w, dv, al);
      if (s < 3) {
        float c = (s == 2) ? dt : 0.5f * dt;
        zt0 = fmaf(c, zd0, z0);
        zt1 = fmaf(c, zd1, z1);
        ts = t0 + c;
      }
    }
    z0 = fmaf(dt / 6.0f, az0, z0);
    z1 = fmaf(dt / 6.0f, az1, z1);
    l = fmaf(-dt / 6.0f, al, l);  // k_l = -div
  }

  out[2 * i] = z0;
  out[2 * i + 1] = z1;
  out[2 * B + i] = l;
}

extern "C" void kernel_launch(void* const* d_in, const int* in_sizes, int n_in,
                              void* d_out, int out_size, void* d_ws, size_t ws_size,
                              hipStream_t stream) {
  const float* z   = (const float*)d_in[0];
  const float* dlp = (const float*)d_in[1];
  const float* W1  = (const float*)d_in[2];
  const float* b1  = (const float*)d_in[3];
  const float* W2  = (const float*)d_in[4];
  const float* b2  = (const float*)d_in[5];
  const float* W3  = (const float*)d_in[6];
  const float* b3  = (const float*)d_in[7];
  float* out = (float*)d_out;
  float* ws = (float*)d_ws;

  int B = in_sizes[0] / 2;

  ffjord_prep<<<1, 256, 0, stream>>>(W1, b1, W2, b2, W3, b3, ws);
  int blocks = (B + 255) / 256;
  ffjord_main<<<blocks, 256, 0, stream>>>(z, dlp, ws, out, B);
}

// Round 4
// 1493.875 us; speedup vs baseline: 4.8610x; 1.4366x over previous
//
#include <hip/hip_runtime.h>

#define HDIM 64
#define NSTEPS 4

typedef float v2f __attribute__((ext_vector_type(2)));

// Packed weight layout in d_ws (float offsets):
//   [0,    256): L1 pack: per k, float4 (W1[k][0], W1[k][1], W1[k][2], b1[k])
//   [256, 4352): W2T[k][j] = W2[j][k+1]                  (64x64)
//   [4352,8448): QT[k][j]  = P[k][j] * W2[j][k+1]        (64x64)
//                where P[k][j] = W1[k][1]*W3[0][j+1] + W1[k][2]*W3[1][j+1]
//   [8448,8576): C2 per j: float2 (W2[j][0], b2[j])
//   [8576,8704): L3 per j: float2 (W3[0][j+1], W3[1][j+1])
//   [8704,8708): C3: (W3[0][0], W3[1][0], b3[0], b3[1])

__global__ void ffjord_prep(const float* __restrict__ W1, const float* __restrict__ b1,
                            const float* __restrict__ W2, const float* __restrict__ b2,
                            const float* __restrict__ W3, const float* __restrict__ b3,
                            float* __restrict__ ws) {
  int tid = threadIdx.x;  // single block, 256 threads
  if (tid < HDIM) {
    ws[tid * 4 + 0] = W1[tid * 3 + 0];
    ws[tid * 4 + 1] = W1[tid * 3 + 1];
    ws[tid * 4 + 2] = W1[tid * 3 + 2];
    ws[tid * 4 + 3] = b1[tid];
    ws[8448 + tid * 2 + 0] = W2[tid * 65 + 0];
    ws[8448 + tid * 2 + 1] = b2[tid];
    ws[8576 + tid * 2 + 0] = W3[0 * 65 + tid + 1];
    ws[8576 + tid * 2 + 1] = W3[1 * 65 + tid + 1];
  }
  if (tid == 0) {
    ws[8704] = W3[0];
    ws[8705] = W3[65];
    ws[8706] = b3[0];
    ws[8707] = b3[1];
  }
  for (int e = tid; e < HDIM * HDIM; e += 256) {
    int k = e >> 6, j = e & 63;
    float w2 = W2[j * 65 + k + 1];
    float p = W1[k * 3 + 1] * W3[j + 1] + W1[k * 3 + 2] * W3[65 + j + 1];
    ws[256 + e] = w2;       // W2T[k][j]
    ws[4352 + e] = p * w2;  // QT[k][j]
  }
}

// Wave-pair split: waves (2g, 2g+1) in a block both handle point group g
// (lane = point); wave half h owns j in [32h, 32h+32). Row bases are
// wave-uniform (readfirstlane -> SGPR) so the s_load broadcast path survives.
// Per-thread live state: h2 slice (16 v2f = 32 regs) + temps ~= 60 regs ->
// fits the (256,4) 64-reg cap -> 4 waves/SIMD. Per-eval partials are combined
// across the wave pair via double-buffered LDS (1 barrier/eval).
__global__ __launch_bounds__(256, 4) void ffjord_main(
    const float* __restrict__ z_in, const float* __restrict__ dlp_in,
    const float* __restrict__ ws, float* __restrict__ out, int B) {
  __shared__ float red[2][256][3];

  int tid = threadIdx.x;
  int lane = tid & 63;
  int half = __builtin_amdgcn_readfirstlane((tid >> 6) & 1);  // j-half (SGPR)
  int grp  = __builtin_amdgcn_readfirstlane(tid >> 7);        // point group (SGPR)
  int i = blockIdx.x * 128 + grp * 64 + lane;
  if (i >= B) i = B - 1;  // clamp; duplicate lanes write identical data

  const float4* L1  = (const float4*)(ws);
  const float*  W2T = ws + 256  + half * 32;   // wave-uniform row base
  const float*  QT  = ws + 4352 + half * 32;
  const float2* C2  = (const float2*)(ws + 8448) + half * 32;
  const float2* L3  = (const float2*)(ws + 8576) + half * 32;
  const float c30 = ws[8704], c31 = ws[8705], cb0 = ws[8706], cb1 = ws[8707];

  float z0 = z_in[2 * i], z1 = z_in[2 * i + 1];
  float l = dlp_in[i];
  const float dt = 1.0f / NSTEPS;
  int rb = 0;  // LDS double-buffer index

  #pragma unroll 1
  for (int step = 0; step < NSTEPS; ++step) {
    float t0 = step * dt;
    float az0 = 0.f, az1 = 0.f, al = 0.f;
    float zt0 = z0, zt1 = z1, ts = t0;

    #pragma unroll 1
    for (int s = 0; s < 4; ++s) {
      // ---- dynamics eval at (ts, zt); this wave covers its 32 j's ----
      // Pass A: h2[j] = W2[:,0]*t + b2 + sum_k W2T[k][j] * softplus(a_k)
      v2f h2[16];
      #pragma unroll
      for (int m = 0; m < 16; ++m) {
        float2 ca = C2[2 * m], cb2 = C2[2 * m + 1];
        v2f v;
        v.x = fmaf(ca.x, ts, ca.y);
        v.y = fmaf(cb2.x, ts, cb2.y);
        h2[m] = v;
      }

      #pragma unroll 1
      for (int k = 0; k < HDIM; ++k) {
        float4 w1 = L1[k];  // wave-uniform -> s_load
        float a = fmaf(w1.x, ts, fmaf(w1.y, zt0, fmaf(w1.z, zt1, w1.w)));
        float e = __expf(-fabsf(a));
        float sp = fmaxf(a, 0.f) + __logf(1.0f + e);   // softplus(a)
        const v2f* w2row = (const v2f*)(W2T + k * 64); // wave-uniform row
        v2f spv = {sp, sp};
        #pragma unroll
        for (int m = 0; m < 16; ++m)
          h2[m] = __builtin_elementwise_fma(w2row[m], spv, h2[m]);
      }

      // Mid: zd partials over my j's; overwrite h2 with g = sigmoid(h2)
      float zd0p = 0.f, zd1p = 0.f;
      #pragma unroll
      for (int m = 0; m < 16; ++m) {
        v2f hv = h2[m];
        v2f gv;
        #pragma unroll
        for (int c = 0; c < 2; ++c) {
          float a = hv[c];
          float e = __expf(-fabsf(a));
          float r = __builtin_amdgcn_rcpf(1.0f + e);
          float sg = (a >= 0.f ? 1.0f : e) * r;        // sigmoid
          float sp = fmaxf(a, 0.f) + __logf(1.0f + e); // softplus
          float2 l3 = L3[2 * m + c];
          zd0p = fmaf(l3.x, sp, zd0p);
          zd1p = fmaf(l3.y, sp, zd1p);
          gv[c] = sg;
        }
        h2[m] = gv;  // now holds g
      }

      // Pass B: dv partial = sum_k sigmoid(a_k) * (QT[k][my j's] . g)
      float dvp = 0.f;
      #pragma unroll 1
      for (int k = 0; k < HDIM; ++k) {
        float4 w1 = L1[k];
        float a = fmaf(w1.x, ts, fmaf(w1.y, zt0, fmaf(w1.z, zt1, w1.w)));
        float e = __expf(-fabsf(a));
        float r = __builtin_amdgcn_rcpf(1.0f + e);
        float sg = (a >= 0.f ? 1.0f : e) * r;          // sigmoid(a_k)
        const v2f* qrow = (const v2f*)(QT + k * 64);   // wave-uniform row
        v2f d0 = {0.f, 0.f}, d1 = {0.f, 0.f};
        #pragma unroll
        for (int m = 0; m < 8; ++m) {
          d0 = __builtin_elementwise_fma(qrow[2 * m], h2[2 * m], d0);
          d1 = __builtin_elementwise_fma(qrow[2 * m + 1], h2[2 * m + 1], d1);
        }
        v2f ds = d0 + d1;
        dvp = fmaf(sg, ds.x + ds.y, dvp);
      }

      // ---- combine partials across the wave pair via LDS ----
      red[rb][tid][0] = zd0p;
      red[rb][tid][1] = zd1p;
      red[rb][tid][2] = dvp;
      __syncthreads();
      int p = tid ^ 64;  // partner wave, same lane
      float zd0 = (zd0p + red[rb][p][0]) + fmaf(c30, ts, cb0);
      float zd1 = (zd1p + red[rb][p][1]) + fmaf(c31, ts, cb1);
      float dv  = dvp + red[rb][p][2];
      rb ^= 1;  // WAR distance 2 evals with a barrier in between -> safe

      // ---- RK4 combine (both waves hold identical zd/dv -> lockstep) ----
      float w = (s == 1 || s == 2) ? 2.0f : 1.0f;
      az0 = fmaf(w, zd0, az0);
      az1 = fmaf(w, zd1, az1);
      al = fmaf(w, dv, al);
      if (s < 3) {
        float c = (s == 2) ? dt : 0.5f * dt;
        zt0 = fmaf(c, zd0, z0);
        zt1 = fmaf(c, zd1, z1);
        ts = t0 + c;
      }
    }
    z0 = fmaf(dt / 6.0f, az0, z0);
    z1 = fmaf(dt / 6.0f, az1, z1);
    l = fmaf(-dt / 6.0f, al, l);  // k_l = -div
  }

  if (half == 0) {
    out[2 * i] = z0;
    out[2 * i + 1] = z1;
  } else {
    out[2 * B + i] = l;
  }
}

extern "C" void kernel_launch(void* const* d_in, const int* in_sizes, int n_in,
                              void* d_out, int out_size, void* d_ws, size_t ws_size,
                              hipStream_t stream) {
  const float* z   = (const float*)d_in[0];
  const float* dlp = (const float*)d_in[1];
  const float* W1  = (const float*)d_in[2];
  const float* b1  = (const float*)d_in[3];
  const float* W2  = (const float*)d_in[4];
  const float* b2  = (const float*)d_in[5];
  const float* W3  = (const float*)d_in[6];
  const float* b3  = (const float*)d_in[7];
  float* out = (float*)d_out;
  float* ws = (float*)d_ws;

  int B = in_sizes[0] / 2;

  ffjord_prep<<<1, 256, 0, stream>>>(W1, b1, W2, b2, W3, b3, ws);
  int blocks = (B + 127) / 128;  // 128 points per block (2 groups x 64)
  ffjord_main<<<blocks, 256, 0, stream>>>(z, dlp, ws, out, B);
}

// Round 5
// 1322.638 us; speedup vs baseline: 5.4903x; 1.1295x over previous
//
#include <hip/hip_runtime.h>

#define HDIM 64
#define NSTEPS 4

typedef float v2f __attribute__((ext_vector_type(2)));

// acc(VGPR pair) += w(SGPR pair, wave-uniform weights) * x(VGPR pair), packed f32.
// hipcc scalarizes __builtin_elementwise_fma on v2f (r3 evidence), so force VOP3P.
#define PK_FMA(acc, w, x) \
  asm("v_pk_fma_f32 %0, %1, %2, %0" : "+v"(acc) : "s"(w), "v"(x))

// Packed weight layout in d_ws (float offsets):
//   [0,    256): L1 pack: per k, float4 (W1[k][0], W1[k][1], W1[k][2], b1[k])
//   [256, 4352): W2T[k][j] = W2[j][k+1]                  (64x64)
//   [4352,8448): QT[k][j]  = P[k][j] * W2[j][k+1]        (64x64)
//                where P[k][j] = W1[k][1]*W3[0][j+1] + W1[k][2]*W3[1][j+1]
//   [8448,8576): C2 per j: float2 (W2[j][0], b2[j])
//   [8576,8704): L3 per j: float2 (W3[0][j+1], W3[1][j+1])
//   [8704,8708): C3: (W3[0][0], W3[1][0], b3[0], b3[1])

__global__ void ffjord_prep(const float* __restrict__ W1, const float* __restrict__ b1,
                            const float* __restrict__ W2, const float* __restrict__ b2,
                            const float* __restrict__ W3, const float* __restrict__ b3,
                            float* __restrict__ ws) {
  int tid = threadIdx.x;  // single block, 256 threads
  if (tid < HDIM) {
    ws[tid * 4 + 0] = W1[tid * 3 + 0];
    ws[tid * 4 + 1] = W1[tid * 3 + 1];
    ws[tid * 4 + 2] = W1[tid * 3 + 2];
    ws[tid * 4 + 3] = b1[tid];
    ws[8448 + tid * 2 + 0] = W2[tid * 65 + 0];
    ws[8448 + tid * 2 + 1] = b2[tid];
    ws[8576 + tid * 2 + 0] = W3[0 * 65 + tid + 1];
    ws[8576 + tid * 2 + 1] = W3[1 * 65 + tid + 1];
  }
  if (tid == 0) {
    ws[8704] = W3[0];
    ws[8705] = W3[65];
    ws[8706] = b3[0];
    ws[8707] = b3[1];
  }
  for (int e = tid; e < HDIM * HDIM; e += 256) {
    int k = e >> 6, j = e & 63;
    float w2 = W2[j * 65 + k + 1];
    float p = W1[k * 3 + 1] * W3[j + 1] + W1[k * 3 + 2] * W3[65 + j + 1];
    ws[256 + e] = w2;       // W2T[k][j]
    ws[4352 + e] = p * w2;  // QT[k][j]
  }
}

// One point per thread; all weight rows wave-uniform (s_load broadcast path).
// Two-pass divergence (pass B recomputes the cheap layer-1 chain) keeps peak
// live state ~= h2(64) + temps ~= 100 regs < the (256,2) 128-reg cap -> no
// spill (r3's spill at exactly 128 was its VALUBusy killer). All j-loop MACs
// forced to v_pk_fma_f32 (SGPR-pair weight x VGPR-pair acc), halving the
// dominant instruction stream vs the scalarized r3.
__global__ __launch_bounds__(256, 2) void ffjord_main(
    const float* __restrict__ z_in, const float* __restrict__ dlp_in,
    const float* __restrict__ ws, float* __restrict__ out, int B) {
  int i = blockIdx.x * 256 + threadIdx.x;
  if (i >= B) return;

  const float4* L1  = (const float4*)(ws);
  const float*  W2T = ws + 256;
  const float*  QT  = ws + 4352;
  const float2* C2  = (const float2*)(ws + 8448);
  const v2f*    L3v = (const v2f*)(ws + 8576);  // per j: (W3[0][j+1], W3[1][j+1])
  const float c30 = ws[8704], c31 = ws[8705], cb0 = ws[8706], cb1 = ws[8707];

  float z0 = z_in[2 * i], z1 = z_in[2 * i + 1];
  float l = dlp_in[i];
  const float dt = 1.0f / NSTEPS;

  #pragma unroll 1
  for (int step = 0; step < NSTEPS; ++step) {
    float t0 = step * dt;
    float az0 = 0.f, az1 = 0.f, al = 0.f;
    float zt0 = z0, zt1 = z1, ts = t0;

    #pragma unroll 1
    for (int s = 0; s < 4; ++s) {
      // ---- dynamics eval at (ts, zt) ----
      // Pass A: h2[j] = W2[:,0]*t + b2 + sum_k W2T[k][j] * softplus(a_k)
      v2f h2[HDIM / 2];
      #pragma unroll
      for (int jj = 0; jj < HDIM / 2; ++jj) {
        float2 ca = C2[2 * jj], cb2 = C2[2 * jj + 1];
        v2f v;
        v.x = fmaf(ca.x, ts, ca.y);
        v.y = fmaf(cb2.x, ts, cb2.y);
        h2[jj] = v;
      }

      #pragma unroll 1
      for (int k = 0; k < HDIM; ++k) {
        float4 w1 = L1[k];  // wave-uniform -> s_load
        float a = fmaf(w1.x, ts, fmaf(w1.y, zt0, fmaf(w1.z, zt1, w1.w)));
        float e = __expf(-fabsf(a));
        float sp = fmaxf(a, 0.f) + __logf(1.0f + e);   // softplus(a)
        const v2f* w2row = (const v2f*)(W2T + k * 64); // wave-uniform row -> SGPRs
        v2f spv = {sp, sp};
        #pragma unroll
        for (int jj = 0; jj < HDIM / 2; ++jj)
          PK_FMA(h2[jj], w2row[jj], spv);
      }

      // Mid: zd(pair) += L3(pair) * softplus(h2_j); overwrite h2 with sigmoid(h2)
      v2f zdv;
      zdv.x = fmaf(c30, ts, cb0);
      zdv.y = fmaf(c31, ts, cb1);
      #pragma unroll
      for (int jj = 0; jj < HDIM / 2; ++jj) {
        v2f hv = h2[jj];
        v2f gv;
        #pragma unroll
        for (int c = 0; c < 2; ++c) {
          float a = hv[c];
          float e = __expf(-fabsf(a));
          float r = __builtin_amdgcn_rcpf(1.0f + e);
          float sg = (a >= 0.f ? 1.0f : e) * r;        // sigmoid
          float sp = fmaxf(a, 0.f) + __logf(1.0f + e); // softplus
          v2f spv = {sp, sp};
          PK_FMA(zdv, L3v[2 * jj + c], spv);           // zd0 += l3.x*sp; zd1 += l3.y*sp
          gv[c] = sg;
        }
        h2[jj] = gv;  // now holds g
      }
      float zd0 = zdv.x, zd1 = zdv.y;

      // Pass B: dv = sum_k sigmoid(a_k) * (QT[k] . g)   (a_k recomputed, cheap)
      float dv = 0.f;
      #pragma unroll 1
      for (int k = 0; k < HDIM; ++k) {
        float4 w1 = L1[k];
        float a = fmaf(w1.x, ts, fmaf(w1.y, zt0, fmaf(w1.z, zt1, w1.w)));
        float e = __expf(-fabsf(a));
        float r = __builtin_amdgcn_rcpf(1.0f + e);
        float sg = (a >= 0.f ? 1.0f : e) * r;          // sigmoid(a_k)
        const v2f* qrow = (const v2f*)(QT + k * 64);   // wave-uniform row -> SGPRs
        v2f d0 = {0.f, 0.f}, d1 = {0.f, 0.f}, d2 = {0.f, 0.f}, d3 = {0.f, 0.f};
        #pragma unroll
        for (int jj = 0; jj < 8; ++jj) {
          PK_FMA(d0, qrow[4 * jj + 0], h2[4 * jj + 0]);
          PK_FMA(d1, qrow[4 * jj + 1], h2[4 * jj + 1]);
          PK_FMA(d2, qrow[4 * jj + 2], h2[4 * jj + 2]);
          PK_FMA(d3, qrow[4 * jj + 3], h2[4 * jj + 3]);
        }
        v2f sab = (d0 + d1) + (d2 + d3);
        dv = fmaf(sg, sab.x + sab.y, dv);
      }

      // ---- RK4 combine ----
      float w = (s == 1 || s == 2) ? 2.0f : 1.0f;
      az0 = fmaf(w, zd0, az0);
      az1 = fmaf(w, zd1, az1);
      al = fmaf(w, dv, al);
      if (s < 3) {
        float c = (s == 2) ? dt : 0.5f * dt;
        zt0 = fmaf(c, zd0, z0);
        zt1 = fmaf(c, zd1, z1);
        ts = t0 + c;
      }
    }
    z0 = fmaf(dt / 6.0f, az0, z0);
    z1 = fmaf(dt / 6.0f, az1, z1);
    l = fmaf(-dt / 6.0f, al, l);  // k_l = -div
  }

  out[2 * i] = z0;
  out[2 * i + 1] = z1;
  out[2 * B + i] = l;
}

extern "C" void kernel_launch(void* const* d_in, const int* in_sizes, int n_in,
                              void* d_out, int out_size, void* d_ws, size_t ws_size,
                              hipStream_t stream) {
  const float* z   = (const float*)d_in[0];
  const float* dlp = (const float*)d_in[1];
  const float* W1  = (const float*)d_in[2];
  const float* b1  = (const float*)d_in[3];
  const float* W2  = (const float*)d_in[4];
  const float* b2  = (const float*)d_in[5];
  const float* W3  = (const float*)d_in[6];
  const float* b3  = (const float*)d_in[7];
  float* out = (float*)d_out;
  float* ws = (float*)d_ws;

  int B = in_sizes[0] / 2;

  ffjord_prep<<<1, 256, 0, stream>>>(W1, b1, W2, b2, W3, b3, ws);
  int blocks = (B + 255) / 256;
  ffjord_main<<<blocks, 256, 0, stream>>>(z, dlp, ws, out, B);
}